// Round 2
// baseline (692.786 us; speedup 1.0000x reference)
//
#include <hip/hip_runtime.h>
#include <hip/hip_bf16.h>
#include <stdint.h>

typedef unsigned short u16;
typedef __bf16 bf16x8 __attribute__((ext_vector_type(8)));
typedef float floatx4 __attribute__((ext_vector_type(4)));

__device__ __forceinline__ u16 f2bf(float f) {
  union { float f; unsigned u; } c; c.f = f;
  unsigned r = c.u + 0x7fffu + ((c.u >> 16) & 1u);
  return (u16)(r >> 16);
}

__device__ __forceinline__ void load_lds16(const void* g, void* l) {
  __builtin_amdgcn_global_load_lds(
      (const __attribute__((address_space(1))) void*)g,
      (__attribute__((address_space(3))) void*)l,
      16, 0, 0);
}

__device__ __forceinline__ void memclob() { asm volatile("" ::: "memory"); }
__device__ __forceinline__ void barrier_() {
  memclob();
  __builtin_amdgcn_s_barrier();
  memclob();
}

// ---- preamble: cast x -> bf16 | transpose W0 | transpose W1 | zero z ----
__global__ __launch_bounds__(256) void preamble(
    const float* __restrict__ x, const float* __restrict__ W0,
    const float* __restrict__ W1,
    u16* __restrict__ Xb, u16* __restrict__ Wt0, u16* __restrict__ Wt1,
    float* __restrict__ z)
{
  __shared__ float tile[32][33];
  const int bid = blockIdx.x;
  const int t = threadIdx.x;

  if (bid < 32768) {                      // cast x: 32768*1024 floats, float4/thread
    int i = bid * 256 + t;
    float4 f = ((const float4*)x)[i];
    ushort4 u;
    u.x = f2bf(f.x); u.y = f2bf(f.y); u.z = f2bf(f.z); u.w = f2bf(f.w);
    ((ushort4*)Xb)[i] = u;
  } else if (bid < 32768 + 2048) {        // transpose W0 [1024,2048] -> [2048,1024]
    int tb = bid - 32768;
    int bx = (tb & 63) * 32, by = (tb >> 6) * 32;
    int tx = t & 31, ty = t >> 5;
    #pragma unroll
    for (int i = 0; i < 32; i += 8)
      tile[ty + i][tx] = W0[(size_t)(by + ty + i) * 2048 + bx + tx];
    __syncthreads();
    #pragma unroll
    for (int i = 0; i < 32; i += 8)
      Wt0[(size_t)(bx + ty + i) * 1024 + by + tx] = f2bf(tile[tx][ty + i]);
  } else if (bid < 32768 + 2048 + 4096) { // transpose W1 [2048,2048]
    int tb = bid - (32768 + 2048);
    int bx = (tb & 63) * 32, by = (tb >> 6) * 32;
    int tx = t & 31, ty = t >> 5;
    #pragma unroll
    for (int i = 0; i < 32; i += 8)
      tile[ty + i][tx] = W1[(size_t)(by + ty + i) * 2048 + bx + tx];
    __syncthreads();
    #pragma unroll
    for (int i = 0; i < 32; i += 8)
      Wt1[(size_t)(bx + ty + i) * 2048 + by + tx] = f2bf(tile[tx][ty + i]);
  } else {                                // zero z[32768]
    int tb = bid - (32768 + 2048 + 4096);
    ((float4*)z)[tb * 256 + t] = (float4){0.f, 0.f, 0.f, 0.f};
  }
}

// ============ 256x256 8-phase GEMM: elu(A[M,K] @ Bt[N,K]^T + bias) ============
// R1 structure (T2+T3+T4+T5, FETCH 571->197MB, 925 TF) + R2 change: K is now a
// TEMPLATE parameter and the main loop is fully branchless — compile-time
// parity, compile-time stage offsets off 4 running pointers, last two K-tiles
// hand-peeled.  R1 post-mortem: MfmaUtil stuck at 40% (vs m201's 62%) with
// VALUBusy only 25% — the barrier-lockstep schedule exposes every scalar
// branch / runtime-K address mul directly on the critical path (1 block/CU:
// nothing else hides it).  This round removes exactly that overhead; the
// memory/LDS/barrier schedule is byte-identical to R1.
template<bool FUSE_HEAD, int KK>
__global__ __launch_bounds__(512, 2) void gemm256_8p(
    const u16* __restrict__ A,      // [M, KK] bf16
    const u16* __restrict__ Bt,     // [N, KK] bf16
    const float* __restrict__ bias, // [N]
    u16* __restrict__ C,            // [M, N] bf16 (unused if FUSE_HEAD)
    const float* __restrict__ W2,   // [N] (used if FUSE_HEAD)
    float* __restrict__ z,          // [M] fp32 accum (used if FUSE_HEAD)
    int M, int N)
{
  __shared__ u16 lds[65536];  // 128 KB; 8 slots x 8192 u16

  const int t = threadIdx.x;
  const int l = t & 63;
  const int w = t >> 6;
  const int wm = w >> 2;       // 0..1
  const int wn = w & 3;        // 0..3
  const int lm = l & 15;
  const int q  = l >> 4;       // 0..3

  // XCD-chunked bijective swizzle; grid = (M/256)*(N/256) = 1024, %8 == 0.
  const int nwg = gridDim.x;
  int wg = blockIdx.x;
  wg = (wg & 7) * (nwg >> 3) + (wg >> 3);
  const int nbn = N >> 8;
  const int n0 = (wg % nbn) << 8;
  const int m0 = (wg / nbn) << 8;

  // ---- staging geometry: per half-tile 2 instrs x 512 thr x 16B = 16 KB.
  // instr n, thread t -> slot-row sr = n*64 + (t>>3), stored chunk t&7,
  // logical chunk (t&7)^((t>>3)&7)  (sr&7 == (t>>3)&7 always). ----
  const int rowoff = t >> 3;                     // 0..63
  const int lc8 = ((t & 7) ^ (rowoff & 7)) * 8;  // logical chunk, u16 units
  const int bq = rowoff >> 5;
  const int br = rowoff & 31;
  // running per-lane pointers, advanced 128 u16 (2 K-tiles) per loop iter
  const u16* rA0 = A  + (size_t)(m0 + rowoff) * KK + lc8;
  const u16* rA1 = A  + (size_t)(m0 + 128 + rowoff) * KK + lc8;
  const u16* rB0 = Bt + (size_t)(n0 + bq * 64 + br) * KK + lc8;
  const u16* rB1 = Bt + (size_t)(n0 + (2 + bq) * 64 + br) * KK + lc8;
  const int ldst = t * 8;                        // u16 dest offset; +4096 for n=1

#define SLOT(p, idx) (((p) * 4 + (idx)) * 8192)  // idx: 0=A-lo 1=A-hi 2=B-lo 3=B-hi

  // stage offsets (S)*64*KK / (S)*32*KK and KOFF are all compile-time.
#define STG_A(P, S, KOFF) do {                                                 \
    load_lds16(rA0 + (S) * 64 * KK + (KOFF), &lds[SLOT(P, S) + ldst]);         \
    load_lds16(rA1 + (S) * 64 * KK + (KOFF), &lds[SLOT(P, S) + 4096 + ldst]);  \
  } while (0)
#define STG_B(P, S, KOFF) do {                                                 \
    load_lds16(rB0 + (S) * 32 * KK + (KOFF), &lds[SLOT(P, 2 + (S)) + ldst]);   \
    load_lds16(rB1 + (S) * 32 * KK + (KOFF), &lds[SLOT(P, 2 + (S)) + 4096 + ldst]); \
  } while (0)

  // ---- read geometry ----
  const int ck0 = ((0 * 4 + q) ^ (lm & 7)) * 8;  // kk=0 swizzled chunk
  const int ck1 = ((1 * 4 + q) ^ (lm & 7)) * 8;  // kk=1
  const int arow = (wm * 64 + lm) * 64;          // + (i&3)*1024
  const int brow = (wn * 32 + lm) * 64;          // + (j&1)*1024
#define RDA(p, i, ck) (*(const bf16x8*)&lds[SLOT(p, (i) >> 2) + arow + ((i) & 3) * 1024 + (ck)])
#define RDB(p, j, ck) (*(const bf16x8*)&lds[SLOT(p, 2 + ((j) >> 1)) + brow + ((j) & 1) * 1024 + (ck)])
#define MFMA(d, x, y) d = __builtin_amdgcn_mfma_f32_16x16x32_bf16(x, y, d, 0, 0, 0)

  floatx4 acc[8][4];
  #pragma unroll
  for (int i = 0; i < 8; ++i)
    #pragma unroll
    for (int j = 0; j < 4; ++j)
      acc[i][j] = (floatx4){0.f, 0.f, 0.f, 0.f};

  bf16x8 a[8][2];   // a-lo live P0-P2, a-hi live P1-P3
  bf16x8 b[2][2];   // b-lo P0-P1, overwritten by b-hi at P2

  constexpr int NK = KK >> 6;
  static_assert(NK >= 4 && (NK & 1) == 0, "NK must be even, >= 4");

#define VMW6 asm volatile("s_waitcnt vmcnt(6)" ::: "memory")
#define VMW0 asm volatile("s_waitcnt vmcnt(0)" ::: "memory")
#define VMWN do {} while (0)

  // One K-tile: 4 phases, each {ds_read subtile | stage | bar | MFMA | bar}.
  // P, SB1, SN2, offsets all compile-time -> zero branches in steady state.
#define KTILE(P, SB1, OB1, SN2, ON2, VMW)                                      \
  {                                                                            \
    _Pragma("unroll")                                                          \
    for (int i = 0; i < 4; ++i) { a[i][0] = RDA(P, i, ck0); a[i][1] = RDA(P, i, ck1); } \
    _Pragma("unroll")                                                          \
    for (int j = 0; j < 2; ++j) { b[j][0] = RDB(P, j, ck0); b[j][1] = RDB(P, j, ck1); } \
    if (SB1) { STG_B((P) ^ 1, 1, OB1); }                                       \
    barrier_();                                                                \
    __builtin_amdgcn_s_setprio(1);                                             \
    _Pragma("unroll")                                                          \
    for (int i = 0; i < 4; ++i)                                                \
      _Pragma("unroll")                                                        \
      for (int j = 0; j < 2; ++j) {                                            \
        MFMA(acc[i][j], a[i][0], b[j][0]);                                     \
        MFMA(acc[i][j], a[i][1], b[j][1]);                                     \
      }                                                                        \
    __builtin_amdgcn_s_setprio(0);                                             \
    barrier_();                                                                \
    _Pragma("unroll")                                                          \
    for (int i = 4; i < 8; ++i) { a[i][0] = RDA(P, i, ck0); a[i][1] = RDA(P, i, ck1); } \
    if (SN2) { STG_A(P, 0, ON2); }                                             \
    barrier_();                                                                \
    __builtin_amdgcn_s_setprio(1);                                             \
    _Pragma("unroll")                                                          \
    for (int i = 4; i < 8; ++i)                                                \
      _Pragma("unroll")                                                        \
      for (int j = 0; j < 2; ++j) {                                            \
        MFMA(acc[i][j], a[i][0], b[j][0]);                                     \
        MFMA(acc[i][j], a[i][1], b[j][1]);                                     \
      }                                                                        \
    __builtin_amdgcn_s_setprio(0);                                             \
    barrier_();                                                                \
    _Pragma("unroll")                                                          \
    for (int j = 0; j < 2; ++j) { b[j][0] = RDB(P, 2 + j, ck0); b[j][1] = RDB(P, 2 + j, ck1); } \
    if (SN2) { STG_A(P, 1, ON2); }                                             \
    barrier_();                                                                \
    __builtin_amdgcn_s_setprio(1);                                             \
    _Pragma("unroll")                                                          \
    for (int i = 0; i < 4; ++i)                                                \
      _Pragma("unroll")                                                        \
      for (int j = 0; j < 2; ++j) {                                            \
        MFMA(acc[i][2 + j], a[i][0], b[j][0]);                                 \
        MFMA(acc[i][2 + j], a[i][1], b[j][1]);                                 \
      }                                                                        \
    __builtin_amdgcn_s_setprio(0);                                             \
    barrier_();                                                                \
    if (SN2) { STG_B(P, 0, ON2); }                                             \
    VMW;                                                                       \
    barrier_();                                                                \
    __builtin_amdgcn_s_setprio(1);                                             \
    _Pragma("unroll")                                                          \
    for (int i = 4; i < 8; ++i)                                                \
      _Pragma("unroll")                                                        \
      for (int j = 0; j < 2; ++j) {                                            \
        MFMA(acc[i][2 + j], a[i][0], b[j][0]);                                 \
        MFMA(acc[i][2 + j], a[i][1], b[j][1]);                                 \
      }                                                                        \
    __builtin_amdgcn_s_setprio(0);                                             \
    barrier_();                                                                \
  }

  // ---- prologue: K-tiles 0 (4 half-tiles) + 1 (A0,A1,B0); 3 stay in flight.
  STG_A(0, 0, 0); memclob(); STG_A(0, 1, 0); memclob();
  STG_B(0, 0, 0); memclob(); STG_B(0, 1, 0); memclob();
  STG_A(1, 0, 64); memclob(); STG_A(1, 1, 64); memclob();
  STG_B(1, 0, 64);
  VMW6;                       // K-tile 0 landed; A0,A1,B0 of K-tile 1 in flight
  barrier_();

  // ---- steady state: 2 K-tiles per iteration, zero branches.
  // K-tile g   (parity 0): stage B1(g+1) @+64, A0/A1/B0(g+2) @+128, vmcnt(6)
  // K-tile g+1 (parity 1): stage B1(g+2) @+128, A0/A1/B0(g+3) @+192, vmcnt(6)
  #pragma unroll 1
  for (int g = 0; g < NK - 2; g += 2) {
    KTILE(0, true, 64, true, 128, VMW6);
    KTILE(1, true, 128, true, 192, VMW6);
    rA0 += 128; rA1 += 128; rB0 += 128; rB1 += 128;
  }
  // ---- peeled tail: K-tile NK-2 stages only B1(NK-1), drains to vmcnt(0);
  // K-tile NK-1 is pure compute.
  KTILE(0, true, 64, false, 0, VMW0);
  KTILE(1, false, 0, false, 0, VMWN);

  // ---------------------------- epilogue ----------------------------
  float bv[4];
  #pragma unroll
  for (int j = 0; j < 4; ++j) bv[j] = bias[n0 + wn * 64 + j * 16 + lm];

  if (!FUSE_HEAD) {
    #pragma unroll
    for (int i = 0; i < 8; ++i) {
      #pragma unroll
      for (int r = 0; r < 4; ++r) {
        int grow = m0 + wm * 128 + i * 16 + q * 4 + r;
        size_t base = (size_t)grow * N + n0 + wn * 64 + lm;
        #pragma unroll
        for (int j = 0; j < 4; ++j) {
          float v = acc[i][j][r] + bv[j];
          v = v > 0.f ? v : (__expf(v) - 1.f);
          C[base + j * 16] = f2bf(v);
        }
      }
    }
  } else {
    float w2v[4];
    #pragma unroll
    for (int j = 0; j < 4; ++j) w2v[j] = W2[n0 + wn * 64 + j * 16 + lm];
    #pragma unroll
    for (int i = 0; i < 8; ++i) {
      #pragma unroll
      for (int r = 0; r < 4; ++r) {
        float pacc = 0.f;
        #pragma unroll
        for (int j = 0; j < 4; ++j) {
          float v = acc[i][j][r] + bv[j];
          v = v > 0.f ? v : (__expf(v) - 1.f);
          pacc += v * w2v[j];
        }
        pacc += __shfl_xor(pacc, 1);
        pacc += __shfl_xor(pacc, 2);
        pacc += __shfl_xor(pacc, 4);
        pacc += __shfl_xor(pacc, 8);
        if (lm == 0) atomicAdd(&z[m0 + wm * 128 + i * 16 + q * 4 + r], pacc);
      }
    }
  }
#undef SLOT
#undef STG_A
#undef STG_B
#undef RDA
#undef RDB
#undef MFMA
#undef KTILE
#undef VMW6
#undef VMW0
#undef VMWN
}

// ------------- finish: out = sigmoid(z + b2); alpha = acti(out) -------------
__global__ __launch_bounds__(256) void sigmoid_alpha(
    const float* __restrict__ z, const float* __restrict__ b2,
    float* __restrict__ out, int B)
{
  int i = blockIdx.x * blockDim.x + threadIdx.x;
  if (i >= B) return;
  float o = 1.f / (1.f + expf(-(z[i] + b2[0])));
  float alpha;
  if (o <= 0.2f)      alpha = 0.1f - 0.5f * o;
  else if (o >= 0.8f) alpha = 0.5f * o - 0.4f;
  else                alpha = 0.f;
  out[i] = o;
  out[B + i] = alpha;
}

extern "C" void kernel_launch(void* const* d_in, const int* in_sizes, int n_in,
                              void* d_out, int out_size, void* d_ws, size_t ws_size,
                              hipStream_t stream) {
  const int BATCH = 32768, HID = 2048;

  const float* x  = (const float*)d_in[0];
  const float* W0 = (const float*)d_in[1];
  const float* b0 = (const float*)d_in[2];
  const float* W1 = (const float*)d_in[3];
  const float* b1 = (const float*)d_in[4];
  const float* W2 = (const float*)d_in[5];
  const float* b2 = (const float*)d_in[6];
  float* out = (float*)d_out;

  char* ws = (char*)d_ws;
  u16* Xb   = (u16*)(ws);                       // 64 MB [32768,1024]
  u16* Wt0  = (u16*)(ws + (size_t)67108864);    // 4 MB  [2048,1024]
  u16* Wt1  = (u16*)(ws + (size_t)71303168);    // 8 MB  [2048,2048]
  u16* h0   = (u16*)(ws + (size_t)79691776);    // 128 MB [32768,2048]
  float* z  = (float*)(ws + (size_t)213909504); // 128 KB [32768]

  const int grid = (BATCH / 256) * (HID / 256); // 1024, divisible by 8

  // 1) preamble: cast x, transpose W0/W1, zero z
  preamble<<<32768 + 2048 + 4096 + 32, 256, 0, stream>>>(x, W0, W1, Xb, Wt0, Wt1, z);
  // 2) h0 = elu(Xb @ Wt0^T + b0)
  gemm256_8p<false, 1024><<<grid, 512, 0, stream>>>(
      Xb, Wt0, b0, h0, nullptr, nullptr, BATCH, HID);
  // 3) z += rows of elu(h0 @ Wt1^T + b1) dotted with W2 (h1 never stored)
  gemm256_8p<true, 2048><<<grid, 512, 0, stream>>>(
      h0, Wt1, b1, nullptr, W2, z, BATCH, HID);
  // 4) out + alpha
  sigmoid_alpha<<<BATCH / 256, 256, 0, stream>>>(z, b2, out, BATCH);
}

// Round 4
// 643.680 us; speedup vs baseline: 1.0763x; 1.0763x over previous
//
#include <hip/hip_runtime.h>
#include <hip/hip_bf16.h>
#include <stdint.h>

typedef unsigned short u16;
typedef __bf16 bf16x8 __attribute__((ext_vector_type(8)));
typedef float floatx4 __attribute__((ext_vector_type(4)));

__device__ __forceinline__ u16 f2bf(float f) {
  union { float f; unsigned u; } c; c.f = f;
  unsigned r = c.u + 0x7fffu + ((c.u >> 16) & 1u);
  return (u16)(r >> 16);
}

__device__ __forceinline__ void load_lds16(const void* g, void* l) {
  __builtin_amdgcn_global_load_lds(
      (const __attribute__((address_space(1))) void*)g,
      (__attribute__((address_space(3))) void*)l,
      16, 0, 0);
}

__device__ __forceinline__ void memclob() { asm volatile("" ::: "memory"); }
__device__ __forceinline__ void barrier_() {
  memclob();
  __builtin_amdgcn_s_barrier();
  memclob();
}

// ---- preamble: cast x -> bf16 | transpose W0 | transpose W1 | zero z ----
__global__ __launch_bounds__(256) void preamble(
    const float* __restrict__ x, const float* __restrict__ W0,
    const float* __restrict__ W1,
    u16* __restrict__ Xb, u16* __restrict__ Wt0, u16* __restrict__ Wt1,
    float* __restrict__ z)
{
  __shared__ float tile[32][33];
  const int bid = blockIdx.x;
  const int t = threadIdx.x;

  if (bid < 32768) {                      // cast x: 32768*1024 floats, float4/thread
    int i = bid * 256 + t;
    float4 f = ((const float4*)x)[i];
    ushort4 u;
    u.x = f2bf(f.x); u.y = f2bf(f.y); u.z = f2bf(f.z); u.w = f2bf(f.w);
    ((ushort4*)Xb)[i] = u;
  } else if (bid < 32768 + 2048) {        // transpose W0 [1024,2048] -> [2048,1024]
    int tb = bid - 32768;
    int bx = (tb & 63) * 32, by = (tb >> 6) * 32;
    int tx = t & 31, ty = t >> 5;
    #pragma unroll
    for (int i = 0; i < 32; i += 8)
      tile[ty + i][tx] = W0[(size_t)(by + ty + i) * 2048 + bx + tx];
    __syncthreads();
    #pragma unroll
    for (int i = 0; i < 32; i += 8)
      Wt0[(size_t)(bx + ty + i) * 1024 + by + tx] = f2bf(tile[tx][ty + i]);
  } else if (bid < 32768 + 2048 + 4096) { // transpose W1 [2048,2048]
    int tb = bid - (32768 + 2048);
    int bx = (tb & 63) * 32, by = (tb >> 6) * 32;
    int tx = t & 31, ty = t >> 5;
    #pragma unroll
    for (int i = 0; i < 32; i += 8)
      tile[ty + i][tx] = W1[(size_t)(by + ty + i) * 2048 + bx + tx];
    __syncthreads();
    #pragma unroll
    for (int i = 0; i < 32; i += 8)
      Wt1[(size_t)(bx + ty + i) * 2048 + by + tx] = f2bf(tile[tx][ty + i]);
  } else {                                // zero z[32768]
    int tb = bid - (32768 + 2048 + 4096);
    ((float4*)z)[tb * 256 + t] = (float4){0.f, 0.f, 0.f, 0.f};
  }
}

// ============ 256x256 GEMM, 4-barrier-per-K-tile (m201 barrier economy) ============
// R4: R1's sub-phase structure but ONE barrier per phase (pre-MFMA), not two.
// Reads+stages issue BEFORE each barrier; lgkm completion rides the barrier
// wait; leading waves drift into the next phase's reads while trailing waves
// finish MFMAs -> LDS pipe (~768cyc/tile @256B/clk) overlaps matrix pipe
// (~620cyc/tile).  R1's post-MFMA barriers forbade that drift -> 40% MfmaUtil.
//
// R3 lesson (absmax fail): stage targets need a barrier AFTER the conflicting
// reads' lgkm-completion point.  With 1 bar/phase the completion points shift:
//   a-lo reads  : complete before each wave's P0 MFMAs -> global at bar1
//   a-hi reads  : global at bar2 ;  b-lo: bar1 ;  b-hi(g): bar3(g)
// Hence the stage schedule (one phase LATER than R1):
//   P0: stage B-hi(g+1)   [conflicting b-hi(g-1) reads global at bar3(g-1)]
//   P2: stage A-lo(g+2)   [post-bar1]
//   P3: stage A-hi(g+2), B-lo(g+2)  [post-bar2], then vmcnt(6)
// FIFO audit at P3's vmcnt(6): 14 outstanding -> retires oldest 8 = ALL of
// tile g+1's loads before bar3 < tile g+1's reads; 6 stay in flight (T4).
// Tail: vmcnt(0) at NK-2; NK-1 pure compute.  Accumulation order == R1
// (bit-identical to the passing R1 run).
template<bool FUSE_HEAD, int KK>
__global__ __launch_bounds__(512, 2) void gemm256_p4(
    const u16* __restrict__ A,      // [M, KK] bf16
    const u16* __restrict__ Bt,     // [N, KK] bf16
    const float* __restrict__ bias, // [N]
    u16* __restrict__ C,            // [M, N] bf16 (unused if FUSE_HEAD)
    const float* __restrict__ W2,   // [N] (used if FUSE_HEAD)
    float* __restrict__ z,          // [M] fp32 accum (used if FUSE_HEAD)
    int M, int N)
{
  __shared__ u16 lds[65536];  // 128 KB; 8 slots x 8192 u16

  const int t = threadIdx.x;
  const int l = t & 63;
  const int w = t >> 6;
  const int wm = w >> 2;       // 0..1
  const int wn = w & 3;        // 0..3
  const int lm = l & 15;
  const int q  = l >> 4;       // 0..3

  // XCD-chunked bijective swizzle; grid = (M/256)*(N/256) = 1024, %8 == 0.
  const int nwg = gridDim.x;
  int wg = blockIdx.x;
  wg = (wg & 7) * (nwg >> 3) + (wg >> 3);
  const int nbn = N >> 8;
  const int n0 = (wg % nbn) << 8;
  const int m0 = (wg / nbn) << 8;

  // ---- staging geometry: per half-tile 2 instrs x 512 thr x 16B = 16 KB.
  // instr n, thread t -> slot-row sr = n*64 + (t>>3), stored chunk t&7,
  // logical chunk (t&7)^((t>>3)&7). ----
  const int rowoff = t >> 3;                     // 0..63
  const int lc8 = ((t & 7) ^ (rowoff & 7)) * 8;  // logical chunk, u16 units
  const int bq = rowoff >> 5;
  const int br = rowoff & 31;
  const u16* rA0 = A  + (size_t)(m0 + rowoff) * KK + lc8;
  const u16* rA1 = A  + (size_t)(m0 + 128 + rowoff) * KK + lc8;
  const u16* rB0 = Bt + (size_t)(n0 + bq * 64 + br) * KK + lc8;
  const u16* rB1 = Bt + (size_t)(n0 + (2 + bq) * 64 + br) * KK + lc8;
  const int ldst = t * 8;                        // u16 dest offset; +4096 for n=1

#define SLOT(p, idx) (((p) * 4 + (idx)) * 8192)  // idx: 0=A-lo 1=A-hi 2=B-lo 3=B-hi

#define STG_A(P, S, KOFF) do {                                                 \
    load_lds16(rA0 + (S) * 64 * KK + (KOFF), &lds[SLOT(P, S) + ldst]);         \
    load_lds16(rA1 + (S) * 64 * KK + (KOFF), &lds[SLOT(P, S) + 4096 + ldst]);  \
  } while (0)
#define STG_B(P, S, KOFF) do {                                                 \
    load_lds16(rB0 + (S) * 32 * KK + (KOFF), &lds[SLOT(P, 2 + (S)) + ldst]);   \
    load_lds16(rB1 + (S) * 32 * KK + (KOFF), &lds[SLOT(P, 2 + (S)) + 4096 + ldst]); \
  } while (0)

  // ---- read geometry ----
  const int ck0 = ((0 * 4 + q) ^ (lm & 7)) * 8;  // kk=0 swizzled chunk
  const int ck1 = ((1 * 4 + q) ^ (lm & 7)) * 8;  // kk=1
  const int arow = (wm * 64 + lm) * 64;          // + (i&3)*1024
  const int brow = (wn * 32 + lm) * 64;          // + (j&1)*1024
#define RDA(p, i, ck) (*(const bf16x8*)&lds[SLOT(p, (i) >> 2) + arow + ((i) & 3) * 1024 + (ck)])
#define RDB(p, j, ck) (*(const bf16x8*)&lds[SLOT(p, 2 + ((j) >> 1)) + brow + ((j) & 1) * 1024 + (ck)])
#define MFMA(d, x, y) d = __builtin_amdgcn_mfma_f32_16x16x32_bf16(x, y, d, 0, 0, 0)

  floatx4 acc[8][4];
  #pragma unroll
  for (int i = 0; i < 8; ++i)
    #pragma unroll
    for (int j = 0; j < 4; ++j)
      acc[i][j] = (floatx4){0.f, 0.f, 0.f, 0.f};

  bf16x8 a0[4][2];   // A-lo fragments (consumed P0 + P2)
  bf16x8 a1[4][2];   // A-hi fragments (consumed P1 + P3)
  bf16x8 bb[2][2];   // b-lo in P0/P1; regs reused for b-hi in P2/P3

  constexpr int NK = KK >> 6;
  static_assert(NK >= 4 && (NK & 1) == 0, "NK must be even, >= 4");

#define VMW6 asm volatile("s_waitcnt vmcnt(6)" ::: "memory")
#define VMW0 asm volatile("s_waitcnt vmcnt(0)" ::: "memory")
#define VMWN do {} while (0)

  // One K-tile: 4 phases, ONE barrier each (pre-MFMA).  Reads + stages issue
  // pre-barrier; compiler places counted lgkm waits before consuming MFMAs.
#define KTILE(P, S1, KO1, S2, KO2, VMW)                                        \
  {                                                                            \
    /* ---- P0: reads a-lo, b-lo | stage B-hi(g+1) | bar0 | MFMA ---- */       \
    _Pragma("unroll")                                                          \
    for (int i = 0; i < 4; ++i) { a0[i][0] = RDA(P, i, ck0); a0[i][1] = RDA(P, i, ck1); } \
    _Pragma("unroll")                                                          \
    for (int j = 0; j < 2; ++j) { bb[j][0] = RDB(P, j, ck0); bb[j][1] = RDB(P, j, ck1); } \
    if (S1) { STG_B((P) ^ 1, 1, KO1); }                                        \
    barrier_();                                                                \
    __builtin_amdgcn_s_setprio(1);                                             \
    _Pragma("unroll")                                                          \
    for (int i = 0; i < 4; ++i)                                                \
      _Pragma("unroll")                                                        \
      for (int j = 0; j < 2; ++j) {                                            \
        MFMA(acc[i][j], a0[i][0], bb[j][0]);                                   \
        MFMA(acc[i][j], a0[i][1], bb[j][1]);                                   \
      }                                                                        \
    __builtin_amdgcn_s_setprio(0);                                             \
    /* ---- P1: reads a-hi | bar1 | MFMA ---- */                               \
    _Pragma("unroll")                                                          \
    for (int i = 0; i < 4; ++i) { a1[i][0] = RDA(P, 4 + i, ck0); a1[i][1] = RDA(P, 4 + i, ck1); } \
    barrier_();                                                                \
    __builtin_amdgcn_s_setprio(1);                                             \
    _Pragma("unroll")                                                          \
    for (int i = 0; i < 4; ++i)                                                \
      _Pragma("unroll")                                                        \
      for (int j = 0; j < 2; ++j) {                                            \
        MFMA(acc[4 + i][j], a1[i][0], bb[j][0]);                               \
        MFMA(acc[4 + i][j], a1[i][1], bb[j][1]);                               \
      }                                                                        \
    __builtin_amdgcn_s_setprio(0);                                             \
    /* ---- P2: reads b-hi (reuse bb) | stage A-lo(g+2) | bar2 | MFMA ---- */  \
    _Pragma("unroll")                                                          \
    for (int j = 0; j < 2; ++j) { bb[j][0] = RDB(P, 2 + j, ck0); bb[j][1] = RDB(P, 2 + j, ck1); } \
    if (S2) { STG_A(P, 0, KO2); }                                              \
    barrier_();                                                                \
    __builtin_amdgcn_s_setprio(1);                                             \
    _Pragma("unroll")                                                          \
    for (int i = 0; i < 4; ++i)                                                \
      _Pragma("unroll")                                                        \
      for (int j = 0; j < 2; ++j) {                                            \
        MFMA(acc[i][2 + j], a0[i][0], bb[j][0]);                               \
        MFMA(acc[i][2 + j], a0[i][1], bb[j][1]);                               \
      }                                                                        \
    __builtin_amdgcn_s_setprio(0);                                             \
    /* ---- P3: stage A-hi(g+2), B-lo(g+2) | vmcnt | bar3 | MFMA ---- */       \
    if (S2) { STG_A(P, 1, KO2); STG_B(P, 0, KO2); }                            \
    VMW;                                                                       \
    barrier_();                                                                \
    __builtin_amdgcn_s_setprio(1);                                             \
    _Pragma("unroll")                                                          \
    for (int i = 0; i < 4; ++i)                                                \
      _Pragma("unroll")                                                        \
      for (int j = 0; j < 2; ++j) {                                            \
        MFMA(acc[4 + i][2 + j], a1[i][0], bb[j][0]);                           \
        MFMA(acc[4 + i][2 + j], a1[i][1], bb[j][1]);                           \
      }                                                                        \
    __builtin_amdgcn_s_setprio(0);                                             \
  }

  // ---- prologue: K-tiles 0 (4 half-tiles) + 1 (A0,A1,B0); vmcnt(6) retires
  // all of tile 0 (14 issued -> oldest 8), leaves tile 1's A/A/B-lo in flight.
  STG_A(0, 0, 0); memclob(); STG_A(0, 1, 0); memclob();
  STG_B(0, 0, 0); memclob(); STG_B(0, 1, 0); memclob();
  STG_A(1, 0, 64); memclob(); STG_A(1, 1, 64); memclob();
  STG_B(1, 0, 64);
  VMW6;
  barrier_();

  // ---- steady state: 2 K-tiles per iteration (compile-time parity).
  #pragma unroll 1
  for (int g = 0; g < NK - 2; g += 2) {
    const int k1 = (g + 1) * 64, k2 = (g + 2) * 64, k3 = (g + 3) * 64;
    KTILE(0, true, k1, true, k2, VMW6);
    KTILE(1, true, k2, true, k3, VMW6);
  }
  // tail: tile NK-2 stages only B-hi(NK-1), drains (8 outstanding -> 0);
  // tile NK-1 pure compute.
  KTILE(0, true, (NK - 1) * 64, false, 0, VMW0);
  KTILE(1, false, 0, false, 0, VMWN);

  // ---------------------------- epilogue ----------------------------
  float bv[4];
  #pragma unroll
  for (int j = 0; j < 4; ++j) bv[j] = bias[n0 + wn * 64 + j * 16 + lm];

  if (!FUSE_HEAD) {
    #pragma unroll
    for (int i = 0; i < 8; ++i) {
      #pragma unroll
      for (int r = 0; r < 4; ++r) {
        int grow = m0 + wm * 128 + i * 16 + q * 4 + r;
        size_t base = (size_t)grow * N + n0 + wn * 64 + lm;
        #pragma unroll
        for (int j = 0; j < 4; ++j) {
          float v = acc[i][j][r] + bv[j];
          v = v > 0.f ? v : (__expf(v) - 1.f);
          C[base + j * 16] = f2bf(v);
        }
      }
    }
  } else {
    float w2v[4];
    #pragma unroll
    for (int j = 0; j < 4; ++j) w2v[j] = W2[n0 + wn * 64 + j * 16 + lm];
    #pragma unroll
    for (int i = 0; i < 8; ++i) {
      #pragma unroll
      for (int r = 0; r < 4; ++r) {
        float pacc = 0.f;
        #pragma unroll
        for (int j = 0; j < 4; ++j) {
          float v = acc[i][j][r] + bv[j];
          v = v > 0.f ? v : (__expf(v) - 1.f);
          pacc += v * w2v[j];
        }
        pacc += __shfl_xor(pacc, 1);
        pacc += __shfl_xor(pacc, 2);
        pacc += __shfl_xor(pacc, 4);
        pacc += __shfl_xor(pacc, 8);
        if (lm == 0) atomicAdd(&z[m0 + wm * 128 + i * 16 + q * 4 + r], pacc);
      }
    }
  }
#undef SLOT
#undef STG_A
#undef STG_B
#undef RDA
#undef RDB
#undef MFMA
#undef KTILE
#undef VMW6
#undef VMW0
#undef VMWN
}

// ------------- finish: out = sigmoid(z + b2); alpha = acti(out) -------------
__global__ __launch_bounds__(256) void sigmoid_alpha(
    const float* __restrict__ z, const float* __restrict__ b2,
    float* __restrict__ out, int B)
{
  int i = blockIdx.x * blockDim.x + threadIdx.x;
  if (i >= B) return;
  float o = 1.f / (1.f + expf(-(z[i] + b2[0])));
  float alpha;
  if (o <= 0.2f)      alpha = 0.1f - 0.5f * o;
  else if (o >= 0.8f) alpha = 0.5f * o - 0.4f;
  else                alpha = 0.f;
  out[i] = o;
  out[B + i] = alpha;
}

extern "C" void kernel_launch(void* const* d_in, const int* in_sizes, int n_in,
                              void* d_out, int out_size, void* d_ws, size_t ws_size,
                              hipStream_t stream) {
  const int BATCH = 32768, HID = 2048;

  const float* x  = (const float*)d_in[0];
  const float* W0 = (const float*)d_in[1];
  const float* b0 = (const float*)d_in[2];
  const float* W1 = (const float*)d_in[3];
  const float* b1 = (const float*)d_in[4];
  const float* W2 = (const float*)d_in[5];
  const float* b2 = (const float*)d_in[6];
  float* out = (float*)d_out;

  char* ws = (char*)d_ws;
  u16* Xb   = (u16*)(ws);                       // 64 MB [32768,1024]
  u16* Wt0  = (u16*)(ws + (size_t)67108864);    // 4 MB  [2048,1024]
  u16* Wt1  = (u16*)(ws + (size_t)71303168);    // 8 MB  [2048,2048]
  u16* h0   = (u16*)(ws + (size_t)79691776);    // 128 MB [32768,2048]
  float* z  = (float*)(ws + (size_t)213909504); // 128 KB [32768]

  const int grid = (BATCH / 256) * (HID / 256); // 1024, divisible by 8

  // 1) preamble: cast x, transpose W0/W1, zero z
  preamble<<<32768 + 2048 + 4096 + 32, 256, 0, stream>>>(x, W0, W1, Xb, Wt0, Wt1, z);
  // 2) h0 = elu(Xb @ Wt0^T + b0)
  gemm256_p4<false, 1024><<<grid, 512, 0, stream>>>(
      Xb, Wt0, b0, h0, nullptr, nullptr, BATCH, HID);
  // 3) z += rows of elu(h0 @ Wt1^T + b1) dotted with W2 (h1 never stored)
  gemm256_p4<true, 2048><<<grid, 512, 0, stream>>>(
      h0, Wt1, b1, nullptr, W2, z, BATCH, HID);
  // 4) out + alpha
  sigmoid_alpha<<<BATCH / 256, 256, 0, stream>>>(z, b2, out, BATCH);
}

// Round 5
// 573.558 us; speedup vs baseline: 1.2079x; 1.1223x over previous
//
#include <hip/hip_runtime.h>
#include <hip/hip_bf16.h>
#include <stdint.h>

typedef unsigned short u16;
typedef __bf16 bf16x8 __attribute__((ext_vector_type(8)));
typedef float floatx4 __attribute__((ext_vector_type(4)));

__device__ __forceinline__ u16 f2bf(float f) {
  union { float f; unsigned u; } c; c.f = f;
  unsigned r = c.u + 0x7fffu + ((c.u >> 16) & 1u);
  return (u16)(r >> 16);
}

__device__ __forceinline__ void load_lds16(const void* g, void* l) {
  __builtin_amdgcn_global_load_lds(
      (const __attribute__((address_space(1))) void*)g,
      (__attribute__((address_space(3))) void*)l,
      16, 0, 0);
}

__device__ __forceinline__ void memclob() { asm volatile("" ::: "memory"); }
__device__ __forceinline__ void barrier_() {
  memclob();
  __builtin_amdgcn_s_barrier();
  memclob();
}

// ---- preamble: cast x -> bf16 | transpose W0 | transpose W1 | zero z ----
__global__ __launch_bounds__(256) void preamble(
    const float* __restrict__ x, const float* __restrict__ W0,
    const float* __restrict__ W1,
    u16* __restrict__ Xb, u16* __restrict__ Wt0, u16* __restrict__ Wt1,
    float* __restrict__ z)
{
  __shared__ float tile[32][33];
  const int bid = blockIdx.x;
  const int t = threadIdx.x;

  if (bid < 32768) {                      // cast x: 32768*1024 floats, float4/thread
    int i = bid * 256 + t;
    float4 f = ((const float4*)x)[i];
    ushort4 u;
    u.x = f2bf(f.x); u.y = f2bf(f.y); u.z = f2bf(f.z); u.w = f2bf(f.w);
    ((ushort4*)Xb)[i] = u;
  } else if (bid < 32768 + 2048) {        // transpose W0 [1024,2048] -> [2048,1024]
    int tb = bid - 32768;
    int bx = (tb & 63) * 32, by = (tb >> 6) * 32;
    int tx = t & 31, ty = t >> 5;
    #pragma unroll
    for (int i = 0; i < 32; i += 8)
      tile[ty + i][tx] = W0[(size_t)(by + ty + i) * 2048 + bx + tx];
    __syncthreads();
    #pragma unroll
    for (int i = 0; i < 32; i += 8)
      Wt0[(size_t)(bx + ty + i) * 1024 + by + tx] = f2bf(tile[tx][ty + i]);
  } else if (bid < 32768 + 2048 + 4096) { // transpose W1 [2048,2048]
    int tb = bid - (32768 + 2048);
    int bx = (tb & 63) * 32, by = (tb >> 6) * 32;
    int tx = t & 31, ty = t >> 5;
    #pragma unroll
    for (int i = 0; i < 32; i += 8)
      tile[ty + i][tx] = W1[(size_t)(by + ty + i) * 2048 + bx + tx];
    __syncthreads();
    #pragma unroll
    for (int i = 0; i < 32; i += 8)
      Wt1[(size_t)(bx + ty + i) * 2048 + by + tx] = f2bf(tile[tx][ty + i]);
  } else {                                // zero z[32768]
    int tb = bid - (32768 + 2048 + 4096);
    ((float4*)z)[tb * 256 + t] = (float4){0.f, 0.f, 0.f, 0.f};
  }
}

// ============ 256x256 GEMM, 4-barrier K-tile, quadrant-ordered phases ============
// R5 = R4's barrier economy (ONE barrier per phase, pre-MFMA) + quadrant
// reorder to cut register pressure (R4 spilled: WRITE_SIZE 16->38MB, arch
// VGPR 128 + 128 unified-acc = 256 cap hit).
//
// Phase order: P0 = a-lo x b-lo, P1 = a-lo x b-hi, P2 = a-hi x b-lo,
// P3 = a-hi x b-hi.  a0 dies after P1, a1 born at P2 -> peak live fragments
// 64 VGPR (was 80).  Reads: P0: a0+b-lo (12), P1: b-hi (4), P2: a1 (8),
// P3: none (P3 has zero lgkm wait).
//
// Stage-hazard audit (completion-global points: a-lo/b-lo @bar1, b-hi @bar2,
// a-hi @bar3):
//   P0: stage A-hi(g+1)        [A-hi(g-1) reads global at bar3(g-1)]
//   P2: stage A-lo,B-lo(g+2)   [post-bar1]
//   P3: stage B-hi(g+2)        [post-bar2], then vmcnt(6)
// FIFO at P3's vmcnt(6): 14 outstanding -> retires oldest 8 = all 4 slots of
// tile g+1, before bar3(g) < tile g+1 reads.  6 stay in flight (T4, never 0
// mid-loop).  Prologue: tile0 x4 + tile1 {A-lo,B-lo,B-hi} = 14 instr,
// vmcnt(6) retires tile 0.  Tail: g=NK-2 stages only A-hi(NK-1), vmcnt(0);
// NK-1 pure compute.  Accumulation order per element unchanged (bit-identical
// output to R1/R4).  Running pointers (R1's no-spill addressing) advanced
// +128 u16 per 2-tile iteration; stage offsets compile-time.
template<bool FUSE_HEAD, int KK>
__global__ __launch_bounds__(512, 2) void gemm256_q4(
    const u16* __restrict__ A,      // [M, KK] bf16
    const u16* __restrict__ Bt,     // [N, KK] bf16
    const float* __restrict__ bias, // [N]
    u16* __restrict__ C,            // [M, N] bf16 (unused if FUSE_HEAD)
    const float* __restrict__ W2,   // [N] (used if FUSE_HEAD)
    float* __restrict__ z,          // [M] fp32 accum (used if FUSE_HEAD)
    int M, int N)
{
  __shared__ u16 lds[65536];  // 128 KB; 8 slots x 8192 u16

  const int t = threadIdx.x;
  const int l = t & 63;
  const int w = t >> 6;
  const int wm = w >> 2;       // 0..1
  const int wn = w & 3;        // 0..3
  const int lm = l & 15;
  const int q  = l >> 4;       // 0..3

  // XCD-chunked bijective swizzle; grid = (M/256)*(N/256) = 1024, %8 == 0.
  const int nwg = gridDim.x;
  int wg = blockIdx.x;
  wg = (wg & 7) * (nwg >> 3) + (wg >> 3);
  const int nbn = N >> 8;
  const int n0 = (wg % nbn) << 8;
  const int m0 = (wg / nbn) << 8;

  // ---- staging geometry: per half-tile 2 instrs x 512 thr x 16B = 16 KB.
  // instr n, thread t -> slot-row sr = n*64 + (t>>3), stored chunk t&7,
  // logical chunk (t&7)^((t>>3)&7). ----
  const int rowoff = t >> 3;                     // 0..63
  const int lc8 = ((t & 7) ^ (rowoff & 7)) * 8;  // logical chunk, u16 units
  const int bq = rowoff >> 5;
  const int br = rowoff & 31;
  // running pointers, advanced 128 u16 (2 K-tiles) per loop iteration
  const u16* rA0 = A  + (size_t)(m0 + rowoff) * KK + lc8;
  const u16* rA1 = A  + (size_t)(m0 + 128 + rowoff) * KK + lc8;
  const u16* rB0 = Bt + (size_t)(n0 + bq * 64 + br) * KK + lc8;
  const u16* rB1 = Bt + (size_t)(n0 + (2 + bq) * 64 + br) * KK + lc8;
  const int ldst = t * 8;                        // u16 dest offset; +4096 for n=1

#define SLOT(p, idx) (((p) * 4 + (idx)) * 8192)  // idx: 0=A-lo 1=A-hi 2=B-lo 3=B-hi

  // S and KOFF compile-time; S*64*KK folds into the address constant.
#define STG_A(P, S, KOFF) do {                                                 \
    load_lds16(rA0 + (S) * 64 * KK + (KOFF), &lds[SLOT(P, S) + ldst]);         \
    load_lds16(rA1 + (S) * 64 * KK + (KOFF), &lds[SLOT(P, S) + 4096 + ldst]);  \
  } while (0)
#define STG_B(P, S, KOFF) do {                                                 \
    load_lds16(rB0 + (S) * 32 * KK + (KOFF), &lds[SLOT(P, 2 + (S)) + ldst]);   \
    load_lds16(rB1 + (S) * 32 * KK + (KOFF), &lds[SLOT(P, 2 + (S)) + 4096 + ldst]); \
  } while (0)

  // ---- read geometry ----
  const int ck0 = ((0 * 4 + q) ^ (lm & 7)) * 8;  // kk=0 swizzled chunk
  const int ck1 = ((1 * 4 + q) ^ (lm & 7)) * 8;  // kk=1
  const int arow = (wm * 64 + lm) * 64;          // + (i&3)*1024
  const int brow = (wn * 32 + lm) * 64;          // + (j&1)*1024
#define RDA(p, i, ck) (*(const bf16x8*)&lds[SLOT(p, (i) >> 2) + arow + ((i) & 3) * 1024 + (ck)])
#define RDB(p, j, ck) (*(const bf16x8*)&lds[SLOT(p, 2 + ((j) >> 1)) + brow + ((j) & 1) * 1024 + (ck)])
#define MFMA(d, x, y) d = __builtin_amdgcn_mfma_f32_16x16x32_bf16(x, y, d, 0, 0, 0)

  floatx4 acc[8][4];
  #pragma unroll
  for (int i = 0; i < 8; ++i)
    #pragma unroll
    for (int j = 0; j < 4; ++j)
      acc[i][j] = (floatx4){0.f, 0.f, 0.f, 0.f};

  bf16x8 a0[4][2];   // a-lo: live P0..P1 only
  bf16x8 a1[4][2];   // a-hi: live P2..P3 only
  bf16x8 bl[2][2];   // b-lo: live P0..P2
  bf16x8 bh[2][2];   // b-hi: live P1..P3

  constexpr int NK = KK >> 6;
  static_assert(NK >= 4 && (NK & 1) == 0, "NK must be even, >= 4");

#define VMW6 asm volatile("s_waitcnt vmcnt(6)" ::: "memory")
#define VMW0 asm volatile("s_waitcnt vmcnt(0)" ::: "memory")
#define VMWN do {} while (0)

  // One K-tile: 4 phases, ONE barrier each (pre-MFMA).
  // SAH = stage A-hi(g+1) at P0; S2 = stage tile g+2 halves at P2/P3.
#define KTILE(P, SAH, KO1, S2, KO2, VMW)                                       \
  {                                                                            \
    /* ---- P0: reads a-lo, b-lo | stage A-hi(g+1) | bar0 | lo x lo ---- */    \
    _Pragma("unroll")                                                          \
    for (int i = 0; i < 4; ++i) { a0[i][0] = RDA(P, i, ck0); a0[i][1] = RDA(P, i, ck1); } \
    _Pragma("unroll")                                                          \
    for (int j = 0; j < 2; ++j) { bl[j][0] = RDB(P, j, ck0); bl[j][1] = RDB(P, j, ck1); } \
    if (SAH) { STG_A((P) ^ 1, 1, KO1); }                                       \
    barrier_();                                                                \
    __builtin_amdgcn_s_setprio(1);                                             \
    _Pragma("unroll")                                                          \
    for (int i = 0; i < 4; ++i)                                                \
      _Pragma("unroll")                                                        \
      for (int j = 0; j < 2; ++j) {                                            \
        MFMA(acc[i][j], a0[i][0], bl[j][0]);                                   \
        MFMA(acc[i][j], a0[i][1], bl[j][1]);                                   \
      }                                                                        \
    __builtin_amdgcn_s_setprio(0);                                             \
    /* ---- P1: reads b-hi | bar1 | lo x hi ---- */                            \
    _Pragma("unroll")                                                          \
    for (int j = 0; j < 2; ++j) { bh[j][0] = RDB(P, 2 + j, ck0); bh[j][1] = RDB(P, 2 + j, ck1); } \
    barrier_();                                                                \
    __builtin_amdgcn_s_setprio(1);                                             \
    _Pragma("unroll")                                                          \
    for (int i = 0; i < 4; ++i)                                                \
      _Pragma("unroll")                                                        \
      for (int j = 0; j < 2; ++j) {                                            \
        MFMA(acc[i][2 + j], a0[i][0], bh[j][0]);                               \
        MFMA(acc[i][2 + j], a0[i][1], bh[j][1]);                               \
      }                                                                        \
    __builtin_amdgcn_s_setprio(0);                                             \
    /* ---- P2: reads a-hi | stage A-lo,B-lo(g+2) | bar2 | hi x lo ---- */     \
    _Pragma("unroll")                                                          \
    for (int i = 0; i < 4; ++i) { a1[i][0] = RDA(P, 4 + i, ck0); a1[i][1] = RDA(P, 4 + i, ck1); } \
    if (S2) { STG_A(P, 0, KO2); STG_B(P, 0, KO2); }                            \
    barrier_();                                                                \
    __builtin_amdgcn_s_setprio(1);                                             \
    _Pragma("unroll")                                                          \
    for (int i = 0; i < 4; ++i)                                                \
      _Pragma("unroll")                                                        \
      for (int j = 0; j < 2; ++j) {                                            \
        MFMA(acc[4 + i][j], a1[i][0], bl[j][0]);                               \
        MFMA(acc[4 + i][j], a1[i][1], bl[j][1]);                               \
      }                                                                        \
    __builtin_amdgcn_s_setprio(0);                                             \
    /* ---- P3: stage B-hi(g+2) | vmcnt | bar3 | hi x hi (no lgkm wait) ---- */\
    if (S2) { STG_B(P, 1, KO2); }                                              \
    VMW;                                                                       \
    barrier_();                                                                \
    __builtin_amdgcn_s_setprio(1);                                             \
    _Pragma("unroll")                                                          \
    for (int i = 0; i < 4; ++i)                                                \
      _Pragma("unroll")                                                        \
      for (int j = 0; j < 2; ++j) {                                            \
        MFMA(acc[4 + i][2 + j], a1[i][0], bh[j][0]);                           \
        MFMA(acc[4 + i][2 + j], a1[i][1], bh[j][1]);                           \
      }                                                                        \
    __builtin_amdgcn_s_setprio(0);                                             \
  }

  // ---- prologue: tile0 {A-lo,A-hi,B-lo,B-hi} + tile1 {A-lo,B-lo,B-hi}
  // (A-hi(1) is staged at P0 of tile 0).  14 instr issued; vmcnt(6) retires
  // the oldest 8 = all of tile 0.
  STG_A(0, 0, 0); memclob(); STG_A(0, 1, 0); memclob();
  STG_B(0, 0, 0); memclob(); STG_B(0, 1, 0); memclob();
  STG_A(1, 0, 64); memclob(); STG_B(1, 0, 64); memclob(); STG_B(1, 1, 64);
  VMW6;
  barrier_();

  // ---- steady state: 2 K-tiles per iteration (compile-time parity).
  // tile g   (p=0): stage A-hi(g+1) @+64,  tile g+2 @+128, vmcnt(6)
  // tile g+1 (p=1): stage A-hi(g+2) @+128, tile g+3 @+192, vmcnt(6)
  #pragma unroll 1
  for (int g = 0; g < NK - 2; g += 2) {
    KTILE(0, true, 64, true, 128, VMW6);
    KTILE(1, true, 128, true, 192, VMW6);
    rA0 += 128; rA1 += 128; rB0 += 128; rB1 += 128;
  }
  // tail: tile NK-2 stages only A-hi(NK-1); 8 outstanding -> drain to 0.
  KTILE(0, true, 64, false, 0, VMW0);
  KTILE(1, false, 0, false, 0, VMWN);

  // ---------------------------- epilogue ----------------------------
  float bv[4];
  #pragma unroll
  for (int j = 0; j < 4; ++j) bv[j] = bias[n0 + wn * 64 + j * 16 + lm];

  if (!FUSE_HEAD) {
    #pragma unroll
    for (int i = 0; i < 8; ++i) {
      #pragma unroll
      for (int r = 0; r < 4; ++r) {
        int grow = m0 + wm * 128 + i * 16 + q * 4 + r;
        size_t base = (size_t)grow * N + n0 + wn * 64 + lm;
        #pragma unroll
        for (int j = 0; j < 4; ++j) {
          float v = acc[i][j][r] + bv[j];
          v = v > 0.f ? v : (__expf(v) - 1.f);
          C[base + j * 16] = f2bf(v);
        }
      }
    }
  } else {
    float w2v[4];
    #pragma unroll
    for (int j = 0; j < 4; ++j) w2v[j] = W2[n0 + wn * 64 + j * 16 + lm];
    #pragma unroll
    for (int i = 0; i < 8; ++i) {
      #pragma unroll
      for (int r = 0; r < 4; ++r) {
        float pacc = 0.f;
        #pragma unroll
        for (int j = 0; j < 4; ++j) {
          float v = acc[i][j][r] + bv[j];
          v = v > 0.f ? v : (__expf(v) - 1.f);
          pacc += v * w2v[j];
        }
        pacc += __shfl_xor(pacc, 1);
        pacc += __shfl_xor(pacc, 2);
        pacc += __shfl_xor(pacc, 4);
        pacc += __shfl_xor(pacc, 8);
        if (lm == 0) atomicAdd(&z[m0 + wm * 128 + i * 16 + q * 4 + r], pacc);
      }
    }
  }
#undef SLOT
#undef STG_A
#undef STG_B
#undef RDA
#undef RDB
#undef MFMA
#undef KTILE
#undef VMW6
#undef VMW0
#undef VMWN
}

// ------------- finish: out = sigmoid(z + b2); alpha = acti(out) -------------
__global__ __launch_bounds__(256) void sigmoid_alpha(
    const float* __restrict__ z, const float* __restrict__ b2,
    float* __restrict__ out, int B)
{
  int i = blockIdx.x * blockDim.x + threadIdx.x;
  if (i >= B) return;
  float o = 1.f / (1.f + expf(-(z[i] + b2[0])));
  float alpha;
  if (o <= 0.2f)      alpha = 0.1f - 0.5f * o;
  else if (o >= 0.8f) alpha = 0.5f * o - 0.4f;
  else                alpha = 0.f;
  out[i] = o;
  out[B + i] = alpha;
}

extern "C" void kernel_launch(void* const* d_in, const int* in_sizes, int n_in,
                              void* d_out, int out_size, void* d_ws, size_t ws_size,
                              hipStream_t stream) {
  const int BATCH = 32768, HID = 2048;

  const float* x  = (const float*)d_in[0];
  const float* W0 = (const float*)d_in[1];
  const float* b0 = (const float*)d_in[2];
  const float* W1 = (const float*)d_in[3];
  const float* b1 = (const float*)d_in[4];
  const float* W2 = (const float*)d_in[5];
  const float* b2 = (const float*)d_in[6];
  float* out = (float*)d_out;

  char* ws = (char*)d_ws;
  u16* Xb   = (u16*)(ws);                       // 64 MB [32768,1024]
  u16* Wt0  = (u16*)(ws + (size_t)67108864);    // 4 MB  [2048,1024]
  u16* Wt1  = (u16*)(ws + (size_t)71303168);    // 8 MB  [2048,2048]
  u16* h0   = (u16*)(ws + (size_t)79691776);    // 128 MB [32768,2048]
  float* z  = (float*)(ws + (size_t)213909504); // 128 KB [32768]

  const int grid = (BATCH / 256) * (HID / 256); // 1024, divisible by 8

  // 1) preamble: cast x, transpose W0/W1, zero z
  preamble<<<32768 + 2048 + 4096 + 32, 256, 0, stream>>>(x, W0, W1, Xb, Wt0, Wt1, z);
  // 2) h0 = elu(Xb @ Wt0^T + b0)
  gemm256_q4<false, 1024><<<grid, 512, 0, stream>>>(
      Xb, Wt0, b0, h0, nullptr, nullptr, BATCH, HID);
  // 3) z += rows of elu(h0 @ Wt1^T + b1) dotted with W2 (h1 never stored)
  gemm256_q4<true, 2048><<<grid, 512, 0, stream>>>(
      h0, Wt1, b1, nullptr, W2, z, BATCH, HID);
  // 4) out + alpha
  sigmoid_alpha<<<BATCH / 256, 256, 0, stream>>>(z, b2, out, BATCH);
}